// Round 1
// baseline (369.674 us; speedup 1.0000x reference)
//
#include <hip/hip_runtime.h>
#include <hip/hip_bf16.h>

// GlobalAttention: B=4, N=2048, D=1024, A=256, f32 in/out.
// out = softmax(  (X Wq + bq) (X Wk + bk)^T + mask ) X
// Pipeline: split/transposes -> proj MFMA (split-bf16 x3) -> scores MFMA
// (split-bf16 x3) -> row softmax (P bf16 in-place) -> PV MFMA -> out.
// Workspace requirement: ~131 MB.

#define BB 4
#define NN 2048
#define DD 1024
#define AA 256

using bf16x8 = __attribute__((ext_vector_type(8))) __bf16;
using f32x4  = __attribute__((ext_vector_type(4))) float;

#define MFMA(a, b, c) __builtin_amdgcn_mfma_f32_16x16x32_bf16(a, b, c, 0, 0, 0)

static __device__ __forceinline__ unsigned short f2bf(float x) {
    union { float f; unsigned int u; } c; c.f = x;
    unsigned int u = c.u;
    u += 0x7fffu + ((u >> 16) & 1u);   // round-to-nearest-even
    return (unsigned short)(u >> 16);
}
static __device__ __forceinline__ float bf2f(unsigned short h) {
    union { unsigned int u; float f; } c; c.u = ((unsigned int)h) << 16;
    return c.f;
}

// ---------- prep: X -> Xh/Xl (row-major bf16 hi/lo) ----------
__global__ __launch_bounds__(256) void k_split(const float* __restrict__ X,
                                               unsigned short* __restrict__ Xh,
                                               unsigned short* __restrict__ Xl) {
    int i = (blockIdx.x * 256 + threadIdx.x) * 4;
    float4 v = *reinterpret_cast<const float4*>(X + i);
    ushort4 h, l;
    h.x = f2bf(v.x); l.x = f2bf(v.x - bf2f(h.x));
    h.y = f2bf(v.y); l.y = f2bf(v.y - bf2f(h.y));
    h.z = f2bf(v.z); l.z = f2bf(v.z - bf2f(h.z));
    h.w = f2bf(v.w); l.w = f2bf(v.w - bf2f(h.w));
    *reinterpret_cast<ushort4*>(Xh + i) = h;
    *reinterpret_cast<ushort4*>(Xl + i) = l;
}

// ---------- prep: X -> XT bf16 [B][D][N] (for PV B-operand) ----------
__global__ __launch_bounds__(256) void k_transpose(const float* __restrict__ X,
                                                   unsigned short* __restrict__ XT) {
    __shared__ unsigned short tile[64][65];
    int t = threadIdx.x;
    int j = t & 63;        // fast index
    int i4 = t >> 6;       // 0..3
    const float* Xb = X + (size_t)blockIdx.z * NN * DD;
    unsigned short* XTb = XT + (size_t)blockIdx.z * DD * NN;
    int n0 = blockIdx.x * 64, d0 = blockIdx.y * 64;
#pragma unroll
    for (int i = i4; i < 64; i += 4)
        tile[i][j] = f2bf(Xb[(size_t)(n0 + i) * DD + d0 + j]);
    __syncthreads();
#pragma unroll
    for (int jj = i4; jj < 64; jj += 4)
        XTb[(size_t)(d0 + jj) * NN + n0 + j] = tile[j][jj];
}

// ---------- prep: W[D][A] -> WT hi/lo bf16 [A][D] ----------
__global__ __launch_bounds__(256) void k_wsplit(const float* __restrict__ W,
                                                unsigned short* __restrict__ WTh,
                                                unsigned short* __restrict__ WTl) {
    int idx = blockIdx.x * 256 + threadIdx.x;  // a-major over AA*DD
    int a = idx >> 10;           // /DD
    int d = idx & (DD - 1);
    float w = W[(size_t)d * AA + a];
    unsigned short hi = f2bf(w);
    WTh[idx] = hi;
    WTl[idx] = f2bf(w - bf2f(hi));
}

// fragment load: A[row][k] row-major, lane holds row=lane&15, k=(lane>>4)*8..+8
static __device__ __forceinline__ bf16x8 ldfrag(const unsigned short* __restrict__ base,
                                                int row, int pitch, int k0, int lane) {
    return *reinterpret_cast<const bf16x8*>(
        base + (size_t)(row + (lane & 15)) * pitch + k0 + ((lane >> 4) << 3));
}

// ---------- proj: O = X W + b  -> split bf16 hi/lo [B*N][A] ----------
__global__ __launch_bounds__(256) void k_proj(const unsigned short* __restrict__ Xh,
                                              const unsigned short* __restrict__ Xl,
                                              const unsigned short* __restrict__ WTh,
                                              const unsigned short* __restrict__ WTl,
                                              const float* __restrict__ bias,
                                              unsigned short* __restrict__ Oh,
                                              unsigned short* __restrict__ Ol) {
    int lane = threadIdx.x & 63;
    int wave = threadIdx.x >> 6;
    int row0 = blockIdx.x * 128 + (wave >> 1) * 64;
    int col0 = blockIdx.y * 128 + (wave & 1) * 64;
    f32x4 acc[4][4] = {};
    for (int k0 = 0; k0 < DD; k0 += 32) {
        bf16x8 ah[4], al[4], bh[4], bl[4];
#pragma unroll
        for (int f = 0; f < 4; ++f) {
            ah[f] = ldfrag(Xh, row0 + f * 16, DD, k0, lane);
            al[f] = ldfrag(Xl, row0 + f * 16, DD, k0, lane);
            bh[f] = ldfrag(WTh, col0 + f * 16, DD, k0, lane);
            bl[f] = ldfrag(WTl, col0 + f * 16, DD, k0, lane);
        }
#pragma unroll
        for (int m = 0; m < 4; ++m)
#pragma unroll
            for (int n = 0; n < 4; ++n) {
                acc[m][n] = MFMA(ah[m], bh[n], acc[m][n]);
                acc[m][n] = MFMA(ah[m], bl[n], acc[m][n]);
                acc[m][n] = MFMA(al[m], bh[n], acc[m][n]);
            }
    }
    int r4 = (lane >> 4) << 2, cl = lane & 15;
#pragma unroll
    for (int m = 0; m < 4; ++m)
#pragma unroll
        for (int n = 0; n < 4; ++n) {
            int col = col0 + n * 16 + cl;
            float bv = bias[col];
#pragma unroll
            for (int r = 0; r < 4; ++r) {
                int row = row0 + m * 16 + r4 + r;
                float v = acc[m][n][r] + bv;
                unsigned short hi = f2bf(v);
                size_t o = (size_t)row * AA + col;
                Oh[o] = hi;
                Ol[o] = f2bf(v - bf2f(hi));
            }
        }
}

// ---------- scores: S[b][n][m] = sum_a Q[n][a] K[m][a]  (f32) ----------
__global__ __launch_bounds__(256) void k_scores(const unsigned short* __restrict__ Qh,
                                                const unsigned short* __restrict__ Ql,
                                                const unsigned short* __restrict__ Kh,
                                                const unsigned short* __restrict__ Kl,
                                                float* __restrict__ S) {
    int lane = threadIdx.x & 63;
    int wave = threadIdx.x >> 6;
    int b = blockIdx.z;
    int nrow0 = blockIdx.x * 128 + (wave >> 1) * 64;
    int mcol0 = blockIdx.y * 128 + (wave & 1) * 64;
    int qrow0 = b * NN + nrow0;
    int krow0 = b * NN + mcol0;
    f32x4 acc[4][4] = {};
    for (int k0 = 0; k0 < AA; k0 += 32) {
        bf16x8 ah[4], al[4], bh[4], bl[4];
#pragma unroll
        for (int f = 0; f < 4; ++f) {
            ah[f] = ldfrag(Qh, qrow0 + f * 16, AA, k0, lane);
            al[f] = ldfrag(Ql, qrow0 + f * 16, AA, k0, lane);
            bh[f] = ldfrag(Kh, krow0 + f * 16, AA, k0, lane);
            bl[f] = ldfrag(Kl, krow0 + f * 16, AA, k0, lane);
        }
#pragma unroll
        for (int m = 0; m < 4; ++m)
#pragma unroll
            for (int n = 0; n < 4; ++n) {
                acc[m][n] = MFMA(ah[m], bh[n], acc[m][n]);
                acc[m][n] = MFMA(ah[m], bl[n], acc[m][n]);
                acc[m][n] = MFMA(al[m], bh[n], acc[m][n]);
            }
    }
    int r4 = (lane >> 4) << 2, cl = lane & 15;
#pragma unroll
    for (int m = 0; m < 4; ++m)
#pragma unroll
        for (int n = 0; n < 4; ++n) {
#pragma unroll
            for (int r = 0; r < 4; ++r) {
                int nrow = nrow0 + m * 16 + r4 + r;
                int mcol = mcol0 + n * 16 + cl;
                S[((size_t)(b * NN + nrow)) * NN + mcol] = acc[m][n][r];
            }
        }
}

// ---------- softmax rows of S (+mask), write P bf16 in-place at row start ----------
__global__ __launch_bounds__(256) void k_softmax(float* __restrict__ S,
                                                 const float* __restrict__ mask) {
    int row = blockIdx.x;          // b*NN + n
    int b = row >> 11;
    float* srow = S + (size_t)row * NN;
    const float* mrow = mask + (size_t)b * NN;
    int t = threadIdx.x;
    float v[8];
    float mx = -3.0e38f;
#pragma unroll
    for (int i = 0; i < 8; ++i) {
        int m = t + i * 256;
        v[i] = srow[m] + mrow[m];
        mx = fmaxf(mx, v[i]);
    }
#pragma unroll
    for (int off = 32; off; off >>= 1) mx = fmaxf(mx, __shfl_xor(mx, off));
    __shared__ float redm[4], reds[4];
    int lane = t & 63, wave = t >> 6;
    if (lane == 0) redm[wave] = mx;
    __syncthreads();
    mx = fmaxf(fmaxf(redm[0], redm[1]), fmaxf(redm[2], redm[3]));
    float s = 0.f;
#pragma unroll
    for (int i = 0; i < 8; ++i) { v[i] = __expf(v[i] - mx); s += v[i]; }
#pragma unroll
    for (int off = 32; off; off >>= 1) s += __shfl_xor(s, off);
    if (lane == 0) reds[wave] = s;
    __syncthreads();
    s = reds[0] + reds[1] + reds[2] + reds[3];
    float inv = 1.0f / s;
    unsigned short* prow = (unsigned short*)srow;   // safe: all reads done pre-barrier
#pragma unroll
    for (int i = 0; i < 8; ++i) {
        int m = t + i * 256;
        prow[m] = f2bf(v[i] * inv);
    }
}

// ---------- PV: out[b][n][d] = sum_m P[n][m] * X[b][m][d] ----------
__global__ __launch_bounds__(256) void k_pv(const float* __restrict__ Sbuf,
                                            const unsigned short* __restrict__ XT,
                                            float* __restrict__ Out) {
    int lane = threadIdx.x & 63;
    int wave = threadIdx.x >> 6;
    int b = blockIdx.z;
    int nrow0 = blockIdx.x * 128 + (wave >> 1) * 64;
    int d0    = blockIdx.y * 128 + (wave & 1) * 64;
    const unsigned short* P = (const unsigned short*)Sbuf;  // rows pitch 2*NN ushorts
    const unsigned short* XTb = XT + (size_t)b * DD * NN;
    int prow0 = b * NN + nrow0;
    f32x4 acc[4][4] = {};
    for (int m0 = 0; m0 < NN; m0 += 32) {
        bf16x8 pa[4], vb[4];
#pragma unroll
        for (int f = 0; f < 4; ++f) {
            pa[f] = ldfrag(P, prow0 + f * 16, NN * 2, m0, lane);
            vb[f] = ldfrag(XTb, d0 + f * 16, NN, m0, lane);
        }
#pragma unroll
        for (int m = 0; m < 4; ++m)
#pragma unroll
            for (int n = 0; n < 4; ++n)
                acc[m][n] = MFMA(pa[m], vb[n], acc[m][n]);
    }
    int r4 = (lane >> 4) << 2, cl = lane & 15;
#pragma unroll
    for (int m = 0; m < 4; ++m)
#pragma unroll
        for (int n = 0; n < 4; ++n) {
#pragma unroll
            for (int r = 0; r < 4; ++r) {
                int row = prow0 + m * 16 + r4 + r;   // b*NN + n
                int dc = d0 + n * 16 + cl;
                Out[(size_t)row * DD + dc] = acc[m][n][r];
            }
        }
}

extern "C" void kernel_launch(void* const* d_in, const int* in_sizes, int n_in,
                              void* d_out, int out_size, void* d_ws, size_t ws_size,
                              hipStream_t stream) {
    const float* X    = (const float*)d_in[0];
    const float* mask = (const float*)d_in[1];
    const float* Wq   = (const float*)d_in[2];
    const float* bq   = (const float*)d_in[3];
    const float* Wk   = (const float*)d_in[4];
    const float* bk   = (const float*)d_in[5];
    float* Out = (float*)d_out;

    // workspace layout (needs ~131 MB)
    unsigned short* Xh   = (unsigned short*)d_ws;
    unsigned short* Xl   = Xh + (size_t)BB * NN * DD;
    unsigned short* XT   = Xl + (size_t)BB * NN * DD;
    unsigned short* WqTh = XT + (size_t)BB * NN * DD;
    unsigned short* WqTl = WqTh + (size_t)AA * DD;
    unsigned short* WkTh = WqTl + (size_t)AA * DD;
    unsigned short* WkTl = WkTh + (size_t)AA * DD;
    unsigned short* Qh   = WkTl + (size_t)AA * DD;
    unsigned short* Ql   = Qh + (size_t)BB * NN * AA;
    unsigned short* Kh   = Ql + (size_t)BB * NN * AA;
    unsigned short* Kl   = Kh + (size_t)BB * NN * AA;
    float* S = (float*)(Kl + (size_t)BB * NN * AA);

    k_split<<<dim3((BB * NN * DD) / 1024), 256, 0, stream>>>(X, Xh, Xl);
    k_transpose<<<dim3(NN / 64, DD / 64, BB), 256, 0, stream>>>(X, XT);
    k_wsplit<<<dim3((AA * DD) / 256), 256, 0, stream>>>(Wq, WqTh, WqTl);
    k_wsplit<<<dim3((AA * DD) / 256), 256, 0, stream>>>(Wk, WkTh, WkTl);

    k_proj<<<dim3((BB * NN) / 128, AA / 128), 256, 0, stream>>>(Xh, Xl, WqTh, WqTl, bq, Qh, Ql);
    k_proj<<<dim3((BB * NN) / 128, AA / 128), 256, 0, stream>>>(Xh, Xl, WkTh, WkTl, bk, Kh, Kl);

    k_scores<<<dim3(NN / 128, NN / 128, BB), 256, 0, stream>>>(Qh, Ql, Kh, Kl, S);
    k_softmax<<<dim3(BB * NN), 256, 0, stream>>>(S, mask);
    k_pv<<<dim3(NN / 128, DD / 128, BB), 256, 0, stream>>>(S, XT, Out);
}

// Round 2
// 174.139 us; speedup vs baseline: 2.1229x; 2.1229x over previous
//
#include <hip/hip_runtime.h>
#include <hip/hip_bf16.h>

// GlobalAttention: B=4, N=2048, D=1024, A=256, f32 in/out.
// out = softmax( (X Wq + bq)(X Wk + bk)^T + mask ) X
// R2: all GEMMs use m97-style LDS staging (global_load_lds x16B, 128x128 tile,
// 2-barrier K-loop) with both-sides XOR slot swizzle for ~conflict-free ds_read_b128.
// Projections for Q and K fused into one launch. Split-bf16 (hi+lo) x3 MFMA for
// proj and scores; plain bf16 for PV. Workspace ~131 MB.

#define BB 4
#define NN 2048
#define DD 1024
#define AA 256

using bf16x8 = __attribute__((ext_vector_type(8))) __bf16;
using f32x4  = __attribute__((ext_vector_type(4))) float;

#define MFMA(a, b, c) __builtin_amdgcn_mfma_f32_16x16x32_bf16(a, b, c, 0, 0, 0)

static __device__ __forceinline__ unsigned short f2bf(float x) {
    union { float f; unsigned int u; } c; c.f = x;
    unsigned int u = c.u;
    u += 0x7fffu + ((u >> 16) & 1u);   // round-to-nearest-even
    return (unsigned short)(u >> 16);
}
static __device__ __forceinline__ float bf2f(unsigned short h) {
    union { unsigned int u; float f; } c; c.u = ((unsigned int)h) << 16;
    return c.f;
}

// ---- swizzle: slot' = slot ^ swz(row); involution, applied on stage-src AND ds_read ----
template<int SLOTS>
static __device__ __forceinline__ int swz(int r) {
    return (SLOTS == 4) ? ((r >> 1) & 3) : (r & 7);
}

// Stage a [128][BK] bf16 tile (row-major, global pitch `pitch` elems) into LDS.
// LDS dest is linear t*16 (wave-uniform base + lane*16 — required by global_load_lds);
// the swizzle is applied by permuting the GLOBAL source slot.
template<int BK>
static __device__ __forceinline__ void stage_tile(const unsigned short* __restrict__ g,
                                                  int pitch, unsigned short* lds, int t) {
    constexpr int SLOTS = BK / 8;                 // 16B slots per row
    constexpr int ISSUES = (128 * SLOTS) / 256;   // per-thread issues
#pragma unroll
    for (int i = 0; i < ISSUES; ++i) {
        int tt = t + i * 256;
        int row = tt / SLOTS;
        int slot = (tt % SLOTS) ^ swz<SLOTS>(row);
        const char* src = (const char*)(g + (size_t)row * pitch) + slot * 16;
        __builtin_amdgcn_global_load_lds((const unsigned int*)src,
                                         (unsigned int*)((char*)lds + (size_t)tt * 16),
                                         16, 0, 0);
    }
}

// Fragment read from staged tile: logical (row + lane&15, k = ks*32 + (lane>>4)*8 ..+8)
template<int BK>
static __device__ __forceinline__ bf16x8 ldsfrag(const unsigned short* lds, int row,
                                                 int ks, int lane) {
    constexpr int SLOTS = BK / 8;
    int r = row + (lane & 15);
    int slot = (ks * 4 + (lane >> 4)) ^ swz<SLOTS>(r);
    return *reinterpret_cast<const bf16x8*>((const char*)lds + (size_t)r * (BK * 2) + slot * 16);
}

// ---------- prep: X -> Xh/Xl (row-major bf16 hi/lo) ----------
__global__ __launch_bounds__(256) void k_split(const float* __restrict__ X,
                                               unsigned short* __restrict__ Xh,
                                               unsigned short* __restrict__ Xl) {
    int i = (blockIdx.x * 256 + threadIdx.x) * 4;
    float4 v = *reinterpret_cast<const float4*>(X + i);
    ushort4 h, l;
    h.x = f2bf(v.x); l.x = f2bf(v.x - bf2f(h.x));
    h.y = f2bf(v.y); l.y = f2bf(v.y - bf2f(h.y));
    h.z = f2bf(v.z); l.z = f2bf(v.z - bf2f(h.z));
    h.w = f2bf(v.w); l.w = f2bf(v.w - bf2f(h.w));
    *reinterpret_cast<ushort4*>(Xh + i) = h;
    *reinterpret_cast<ushort4*>(Xl + i) = l;
}

// ---------- prep: X -> XT bf16 [B][D][N] ----------
__global__ __launch_bounds__(256) void k_transpose(const float* __restrict__ X,
                                                   unsigned short* __restrict__ XT) {
    __shared__ unsigned short tile[64][65];
    int t = threadIdx.x;
    int j = t & 63;
    int i4 = t >> 6;
    const float* Xb = X + (size_t)blockIdx.z * NN * DD;
    unsigned short* XTb = XT + (size_t)blockIdx.z * DD * NN;
    int n0 = blockIdx.x * 64, d0 = blockIdx.y * 64;
#pragma unroll
    for (int i = i4; i < 64; i += 4)
        tile[i][j] = f2bf(Xb[(size_t)(n0 + i) * DD + d0 + j]);
    __syncthreads();
#pragma unroll
    for (int jj = i4; jj < 64; jj += 4)
        XTb[(size_t)(d0 + jj) * NN + n0 + j] = tile[j][jj];
}

// ---------- prep: W[D][A] -> WT hi/lo bf16 [A][D] ----------
__global__ __launch_bounds__(256) void k_wsplit(const float* __restrict__ W,
                                                unsigned short* __restrict__ WTh,
                                                unsigned short* __restrict__ WTl) {
    int idx = blockIdx.x * 256 + threadIdx.x;
    int a = idx >> 10;
    int d = idx & (DD - 1);
    float w = W[(size_t)d * AA + a];
    unsigned short hi = f2bf(w);
    WTh[idx] = hi;
    WTl[idx] = f2bf(w - bf2f(hi));
}

// ---------- fused proj: {Q,K} = X W{q,k} + b  -> split bf16 [B*N][A] ----------
// grid (64, 4): y>>1 selects Q/K, y&1 selects col half.
__global__ __launch_bounds__(256) void k_proj(const unsigned short* __restrict__ Xh,
                                              const unsigned short* __restrict__ Xl,
                                              const unsigned short* __restrict__ WqTh,
                                              const unsigned short* __restrict__ WqTl,
                                              const unsigned short* __restrict__ WkTh,
                                              const unsigned short* __restrict__ WkTl,
                                              const float* __restrict__ bq,
                                              const float* __restrict__ bk,
                                              unsigned short* __restrict__ Qh,
                                              unsigned short* __restrict__ Ql,
                                              unsigned short* __restrict__ Kh,
                                              unsigned short* __restrict__ Kl) {
    __shared__ unsigned short ldsAh[128 * 32], ldsAl[128 * 32];
    __shared__ unsigned short ldsBh[128 * 32], ldsBl[128 * 32];
    int t = threadIdx.x, lane = t & 63, wave = t >> 6;
    int row0 = blockIdx.x * 128;
    int which = blockIdx.y >> 1;
    int col0 = (blockIdx.y & 1) * 128;
    const unsigned short* BTh = which ? WkTh : WqTh;
    const unsigned short* BTl = which ? WkTl : WqTl;
    const float* bias = which ? bk : bq;
    unsigned short* Oh = which ? Kh : Qh;
    unsigned short* Ol = which ? Kl : Ql;
    int wr = (wave >> 1) * 64, wc = (wave & 1) * 64;
    f32x4 acc[4][4] = {};
    for (int k0 = 0; k0 < DD; k0 += 32) {
        __syncthreads();
        stage_tile<32>(Xh + (size_t)row0 * DD + k0, DD, ldsAh, t);
        stage_tile<32>(Xl + (size_t)row0 * DD + k0, DD, ldsAl, t);
        stage_tile<32>(BTh + (size_t)col0 * DD + k0, DD, ldsBh, t);
        stage_tile<32>(BTl + (size_t)col0 * DD + k0, DD, ldsBl, t);
        __syncthreads();
        bf16x8 ah[4], al[4], bh[4], bl[4];
#pragma unroll
        for (int f = 0; f < 4; ++f) {
            ah[f] = ldsfrag<32>(ldsAh, wr + f * 16, 0, lane);
            al[f] = ldsfrag<32>(ldsAl, wr + f * 16, 0, lane);
            bh[f] = ldsfrag<32>(ldsBh, wc + f * 16, 0, lane);
            bl[f] = ldsfrag<32>(ldsBl, wc + f * 16, 0, lane);
        }
#pragma unroll
        for (int m = 0; m < 4; ++m)
#pragma unroll
            for (int n = 0; n < 4; ++n) {
                acc[m][n] = MFMA(ah[m], bh[n], acc[m][n]);
                acc[m][n] = MFMA(ah[m], bl[n], acc[m][n]);
                acc[m][n] = MFMA(al[m], bh[n], acc[m][n]);
            }
    }
    int r4 = (lane >> 4) << 2, cl = lane & 15;
#pragma unroll
    for (int m = 0; m < 4; ++m)
#pragma unroll
        for (int n = 0; n < 4; ++n) {
            int col = col0 + wc + n * 16 + cl;
            float bv = bias[col];
#pragma unroll
            for (int r = 0; r < 4; ++r) {
                int row = row0 + wr + m * 16 + r4 + r;
                float v = acc[m][n][r] + bv;
                unsigned short hi = f2bf(v);
                size_t o = (size_t)row * AA + col;
                Oh[o] = hi;
                Ol[o] = f2bf(v - bf2f(hi));
            }
        }
}

// ---------- scores: S[b][n][m] = sum_a Q[n][a] K[m][a]  (f32) ----------
__global__ __launch_bounds__(256) void k_scores(const unsigned short* __restrict__ Qh,
                                                const unsigned short* __restrict__ Ql,
                                                const unsigned short* __restrict__ Kh,
                                                const unsigned short* __restrict__ Kl,
                                                float* __restrict__ S) {
    __shared__ unsigned short ldsAh[128 * 32], ldsAl[128 * 32];
    __shared__ unsigned short ldsBh[128 * 32], ldsBl[128 * 32];
    int t = threadIdx.x, lane = t & 63, wave = t >> 6;
    int b = blockIdx.z;
    int nrow0 = blockIdx.x * 128;
    int mcol0 = blockIdx.y * 128;
    size_t qbase = (size_t)(b * NN + nrow0) * AA;
    size_t kbase = (size_t)(b * NN + mcol0) * AA;
    int wr = (wave >> 1) * 64, wc = (wave & 1) * 64;
    f32x4 acc[4][4] = {};
    for (int k0 = 0; k0 < AA; k0 += 32) {
        __syncthreads();
        stage_tile<32>(Qh + qbase + k0, AA, ldsAh, t);
        stage_tile<32>(Ql + qbase + k0, AA, ldsAl, t);
        stage_tile<32>(Kh + kbase + k0, AA, ldsBh, t);
        stage_tile<32>(Kl + kbase + k0, AA, ldsBl, t);
        __syncthreads();
        bf16x8 ah[4], al[4], bh[4], bl[4];
#pragma unroll
        for (int f = 0; f < 4; ++f) {
            ah[f] = ldsfrag<32>(ldsAh, wr + f * 16, 0, lane);
            al[f] = ldsfrag<32>(ldsAl, wr + f * 16, 0, lane);
            bh[f] = ldsfrag<32>(ldsBh, wc + f * 16, 0, lane);
            bl[f] = ldsfrag<32>(ldsBl, wc + f * 16, 0, lane);
        }
#pragma unroll
        for (int m = 0; m < 4; ++m)
#pragma unroll
            for (int n = 0; n < 4; ++n) {
                acc[m][n] = MFMA(ah[m], bh[n], acc[m][n]);
                acc[m][n] = MFMA(ah[m], bl[n], acc[m][n]);
                acc[m][n] = MFMA(al[m], bh[n], acc[m][n]);
            }
    }
    int r4 = (lane >> 4) << 2, cl = lane & 15;
#pragma unroll
    for (int m = 0; m < 4; ++m)
#pragma unroll
        for (int n = 0; n < 4; ++n) {
#pragma unroll
            for (int r = 0; r < 4; ++r) {
                int nrow = nrow0 + wr + m * 16 + r4 + r;
                int mcol = mcol0 + wc + n * 16 + cl;
                S[((size_t)(b * NN + nrow)) * NN + mcol] = acc[m][n][r];
            }
        }
}

// ---------- softmax rows of S (+mask), write P bf16 in-place at row start ----------
__global__ __launch_bounds__(256) void k_softmax(float* __restrict__ S,
                                                 const float* __restrict__ mask) {
    int row = blockIdx.x;          // b*NN + n
    int b = row >> 11;
    float* srow = S + (size_t)row * NN;
    const float* mrow = mask + (size_t)b * NN;
    int t = threadIdx.x;
    float v[8];
    float mx = -3.0e38f;
#pragma unroll
    for (int i = 0; i < 8; ++i) {
        int m = t + i * 256;
        v[i] = srow[m] + mrow[m];
        mx = fmaxf(mx, v[i]);
    }
#pragma unroll
    for (int off = 32; off; off >>= 1) mx = fmaxf(mx, __shfl_xor(mx, off));
    __shared__ float redm[4], reds[4];
    int lane = t & 63, wave = t >> 6;
    if (lane == 0) redm[wave] = mx;
    __syncthreads();
    mx = fmaxf(fmaxf(redm[0], redm[1]), fmaxf(redm[2], redm[3]));
    float s = 0.f;
#pragma unroll
    for (int i = 0; i < 8; ++i) { v[i] = __expf(v[i] - mx); s += v[i]; }
#pragma unroll
    for (int off = 32; off; off >>= 1) s += __shfl_xor(s, off);
    if (lane == 0) reds[wave] = s;
    __syncthreads();
    s = reds[0] + reds[1] + reds[2] + reds[3];
    float inv = 1.0f / s;
    unsigned short* prow = (unsigned short*)srow;   // all reads done pre-barrier
#pragma unroll
    for (int i = 0; i < 8; ++i) {
        int m = t + i * 256;
        prow[m] = f2bf(v[i] * inv);
    }
}

// ---------- PV: out[b][n][d] = sum_m P[n][m] * X[b][m][d] ----------
__global__ __launch_bounds__(256) void k_pv(const float* __restrict__ Sbuf,
                                            const unsigned short* __restrict__ XT,
                                            float* __restrict__ Out) {
    __shared__ unsigned short ldsA[128 * 64], ldsB[128 * 64];
    int t = threadIdx.x, lane = t & 63, wave = t >> 6;
    int b = blockIdx.z;
    int nrow0 = blockIdx.x * 128;
    int d0    = blockIdx.y * 128;
    const unsigned short* P = (const unsigned short*)Sbuf;  // row pitch 2*NN ushorts
    const unsigned short* XTb = XT + (size_t)b * DD * NN;
    size_t pbase = (size_t)(b * NN + nrow0) * (NN * 2);
    int wr = (wave >> 1) * 64, wc = (wave & 1) * 64;
    f32x4 acc[4][4] = {};
    for (int m0 = 0; m0 < NN; m0 += 64) {
        __syncthreads();
        stage_tile<64>(P + pbase + m0, NN * 2, ldsA, t);
        stage_tile<64>(XTb + (size_t)d0 * NN + m0, NN, ldsB, t);
        __syncthreads();
        bf16x8 pa[2][4], vb[2][4];
#pragma unroll
        for (int ks = 0; ks < 2; ++ks)
#pragma unroll
            for (int f = 0; f < 4; ++f) {
                pa[ks][f] = ldsfrag<64>(ldsA, wr + f * 16, ks, lane);
                vb[ks][f] = ldsfrag<64>(ldsB, wc + f * 16, ks, lane);
            }
#pragma unroll
        for (int ks = 0; ks < 2; ++ks)
#pragma unroll
            for (int m = 0; m < 4; ++m)
#pragma unroll
                for (int n = 0; n < 4; ++n)
                    acc[m][n] = MFMA(pa[ks][m], vb[ks][n], acc[m][n]);
    }
    int r4 = (lane >> 4) << 2, cl = lane & 15;
#pragma unroll
    for (int m = 0; m < 4; ++m)
#pragma unroll
        for (int n = 0; n < 4; ++n) {
#pragma unroll
            for (int r = 0; r < 4; ++r) {
                int row = b * NN + nrow0 + wr + m * 16 + r4 + r;
                int dc = d0 + wc + n * 16 + cl;
                Out[(size_t)row * DD + dc] = acc[m][n][r];
            }
        }
}

extern "C" void kernel_launch(void* const* d_in, const int* in_sizes, int n_in,
                              void* d_out, int out_size, void* d_ws, size_t ws_size,
                              hipStream_t stream) {
    const float* X    = (const float*)d_in[0];
    const float* mask = (const float*)d_in[1];
    const float* Wq   = (const float*)d_in[2];
    const float* bq   = (const float*)d_in[3];
    const float* Wk   = (const float*)d_in[4];
    const float* bk   = (const float*)d_in[5];
    float* Out = (float*)d_out;

    unsigned short* Xh   = (unsigned short*)d_ws;
    unsigned short* Xl   = Xh + (size_t)BB * NN * DD;
    unsigned short* XT   = Xl + (size_t)BB * NN * DD;
    unsigned short* WqTh = XT + (size_t)BB * NN * DD;
    unsigned short* WqTl = WqTh + (size_t)AA * DD;
    unsigned short* WkTh = WqTl + (size_t)AA * DD;
    unsigned short* WkTl = WkTh + (size_t)AA * DD;
    unsigned short* Qh   = WkTl + (size_t)AA * DD;
    unsigned short* Ql   = Qh + (size_t)BB * NN * AA;
    unsigned short* Kh   = Ql + (size_t)BB * NN * AA;
    unsigned short* Kl   = Kh + (size_t)BB * NN * AA;
    float* S = (float*)(Kl + (size_t)BB * NN * AA);

    k_split<<<dim3((BB * NN * DD) / 1024), 256, 0, stream>>>(X, Xh, Xl);
    k_transpose<<<dim3(NN / 64, DD / 64, BB), 256, 0, stream>>>(X, XT);
    k_wsplit<<<dim3((AA * DD) / 256), 256, 0, stream>>>(Wq, WqTh, WqTl);
    k_wsplit<<<dim3((AA * DD) / 256), 256, 0, stream>>>(Wk, WkTh, WkTl);

    k_proj<<<dim3((BB * NN) / 128, 4), 256, 0, stream>>>(Xh, Xl, WqTh, WqTl, WkTh, WkTl,
                                                         bq, bk, Qh, Ql, Kh, Kl);

    k_scores<<<dim3(NN / 128, NN / 128, BB), 256, 0, stream>>>(Qh, Ql, Kh, Kl, S);
    k_softmax<<<dim3(BB * NN), 256, 0, stream>>>(S, mask);
    k_pv<<<dim3(NN / 128, DD / 128, BB), 256, 0, stream>>>(S, XT, Out);
}

// Round 3
// 169.206 us; speedup vs baseline: 2.1847x; 1.0291x over previous
//
#include <hip/hip_runtime.h>
#include <hip/hip_bf16.h>

// GlobalAttention: B=4, N=2048, D=1024, A=256, f32 in/out.
// out = softmax( (X Wq + bq)(X Wk + bk)^T + mask ) X
// R3: all GEMMs use 2-phase double-buffered LDS (stage t+1 issued before
// compute of t, ONE barrier per K-step) to hide the global_load_lds drain
// that capped MfmaUtil at 26%. Both-sides XOR slot swizzle kept. Fused prep
// (X -> Xh/Xl/XT in one pass). Split-bf16 x3 for proj+scores, bf16 PV.

#define BB 4
#define NN 2048
#define DD 1024
#define AA 256

using bf16x8 = __attribute__((ext_vector_type(8))) __bf16;
using f32x4  = __attribute__((ext_vector_type(4))) float;

#define MFMA(a, b, c) __builtin_amdgcn_mfma_f32_16x16x32_bf16(a, b, c, 0, 0, 0)

static __device__ __forceinline__ unsigned short f2bf(float x) {
    union { float f; unsigned int u; } c; c.f = x;
    unsigned int u = c.u;
    u += 0x7fffu + ((u >> 16) & 1u);   // round-to-nearest-even
    return (unsigned short)(u >> 16);
}
static __device__ __forceinline__ float bf2f(unsigned short h) {
    union { unsigned int u; float f; } c; c.u = ((unsigned int)h) << 16;
    return c.f;
}

// ---- swizzle: slot' = slot ^ swz(row); involution on stage-src AND ds_read ----
template<int SLOTS>
static __device__ __forceinline__ int swz(int r) {
    return (SLOTS == 4) ? ((r >> 1) & 3) : (r & 7);
}

// Stage a [128][BK] bf16 tile into LDS; linear LDS dest (global_load_lds
// requirement), swizzle applied by permuting the GLOBAL source slot.
template<int BK>
static __device__ __forceinline__ void stage_tile(const unsigned short* __restrict__ g,
                                                  int pitch, unsigned short* lds, int t) {
    constexpr int SLOTS = BK / 8;
    constexpr int ISSUES = (128 * SLOTS) / 256;
#pragma unroll
    for (int i = 0; i < ISSUES; ++i) {
        int tt = t + i * 256;
        int row = tt / SLOTS;
        int slot = (tt % SLOTS) ^ swz<SLOTS>(row);
        const char* src = (const char*)(g + (size_t)row * pitch) + slot * 16;
        __builtin_amdgcn_global_load_lds((const unsigned int*)src,
                                         (unsigned int*)((char*)lds + (size_t)tt * 16),
                                         16, 0, 0);
    }
}

template<int BK>
static __device__ __forceinline__ bf16x8 ldsfrag(const unsigned short* lds, int row,
                                                 int ks, int lane) {
    constexpr int SLOTS = BK / 8;
    int r = row + (lane & 15);
    int slot = (ks * 4 + (lane >> 4)) ^ swz<SLOTS>(r);
    return *reinterpret_cast<const bf16x8*>((const char*)lds + (size_t)r * (BK * 2) + slot * 16);
}

// ---------- fused prep: X -> Xh, Xl (row-major) and XT bf16 [B][D][N] ----------
__global__ __launch_bounds__(256) void k_prep(const float* __restrict__ X,
                                              unsigned short* __restrict__ Xh,
                                              unsigned short* __restrict__ Xl,
                                              unsigned short* __restrict__ XT) {
    __shared__ unsigned short tile[64][65];   // [d][n], hi values
    int t = threadIdx.x;
    int n0 = blockIdx.x * 64, d0 = blockIdx.y * 64;
    const float* Xb = X + (size_t)blockIdx.z * NN * DD;
    unsigned short* Xhb = Xh + (size_t)blockIdx.z * NN * DD;
    unsigned short* Xlb = Xl + (size_t)blockIdx.z * NN * DD;
    unsigned short* XTb = XT + (size_t)blockIdx.z * DD * NN;
    int r = t >> 4, c4 = (t & 15) * 4;
#pragma unroll
    for (int i = 0; i < 4; ++i) {
        int row = r + 16 * i;
        float4 v = *reinterpret_cast<const float4*>(Xb + (size_t)(n0 + row) * DD + d0 + c4);
        ushort4 h, l;
        h.x = f2bf(v.x); l.x = f2bf(v.x - bf2f(h.x));
        h.y = f2bf(v.y); l.y = f2bf(v.y - bf2f(h.y));
        h.z = f2bf(v.z); l.z = f2bf(v.z - bf2f(h.z));
        h.w = f2bf(v.w); l.w = f2bf(v.w - bf2f(h.w));
        *reinterpret_cast<ushort4*>(Xhb + (size_t)(n0 + row) * DD + d0 + c4) = h;
        *reinterpret_cast<ushort4*>(Xlb + (size_t)(n0 + row) * DD + d0 + c4) = l;
        tile[c4 + 0][row] = h.x;
        tile[c4 + 1][row] = h.y;
        tile[c4 + 2][row] = h.z;
        tile[c4 + 3][row] = h.w;
    }
    __syncthreads();
    int j = t & 63, i4 = t >> 6;
#pragma unroll
    for (int jj = i4; jj < 64; jj += 4)
        XTb[(size_t)(d0 + jj) * NN + n0 + j] = tile[jj][j];
}

// ---------- prep: W[D][A] -> WT hi/lo bf16 [A][D] ----------
__global__ __launch_bounds__(256) void k_wsplit(const float* __restrict__ W,
                                                unsigned short* __restrict__ WTh,
                                                unsigned short* __restrict__ WTl) {
    int idx = blockIdx.x * 256 + threadIdx.x;
    int a = idx >> 10;
    int d = idx & (DD - 1);
    float w = W[(size_t)d * AA + a];
    unsigned short hi = f2bf(w);
    WTh[idx] = hi;
    WTl[idx] = f2bf(w - bf2f(hi));
}

// ---------- fused proj: {Q,K} = X W{q,k} + b -> split bf16 [B*N][A] ----------
// grid (64, 4): y>>1 selects Q/K, y&1 selects col half. 2-phase dbuf.
__global__ __launch_bounds__(256) void k_proj(const unsigned short* __restrict__ Xh,
                                              const unsigned short* __restrict__ Xl,
                                              const unsigned short* __restrict__ WqTh,
                                              const unsigned short* __restrict__ WqTl,
                                              const unsigned short* __restrict__ WkTh,
                                              const unsigned short* __restrict__ WkTl,
                                              const float* __restrict__ bq,
                                              const float* __restrict__ bk,
                                              unsigned short* __restrict__ Qh,
                                              unsigned short* __restrict__ Ql,
                                              unsigned short* __restrict__ Kh,
                                              unsigned short* __restrict__ Kl) {
    __shared__ unsigned short ldsAh[2][128 * 32], ldsAl[2][128 * 32];
    __shared__ unsigned short ldsBh[2][128 * 32], ldsBl[2][128 * 32];
    int t = threadIdx.x, lane = t & 63, wave = t >> 6;
    int row0 = blockIdx.x * 128;
    int which = blockIdx.y >> 1;
    int col0 = (blockIdx.y & 1) * 128;
    const unsigned short* BTh = which ? WkTh : WqTh;
    const unsigned short* BTl = which ? WkTl : WqTl;
    const float* bias = which ? bk : bq;
    unsigned short* Oh = which ? Kh : Qh;
    unsigned short* Ol = which ? Kl : Ql;
    const unsigned short* Abase_h = Xh + (size_t)row0 * DD;
    const unsigned short* Abase_l = Xl + (size_t)row0 * DD;
    const unsigned short* Bbase_h = BTh + (size_t)col0 * DD;
    const unsigned short* Bbase_l = BTl + (size_t)col0 * DD;
    int wr = (wave >> 1) * 64, wc = (wave & 1) * 64;
    f32x4 acc[4][4] = {};
    stage_tile<32>(Abase_h, DD, ldsAh[0], t);
    stage_tile<32>(Abase_l, DD, ldsAl[0], t);
    stage_tile<32>(Bbase_h, DD, ldsBh[0], t);
    stage_tile<32>(Bbase_l, DD, ldsBl[0], t);
    __syncthreads();
    constexpr int NT = DD / 32;
    for (int tt = 0; tt < NT; ++tt) {
        int cur = tt & 1;
        if (tt + 1 < NT) {
            int k0 = (tt + 1) * 32;
            stage_tile<32>(Abase_h + k0, DD, ldsAh[cur ^ 1], t);
            stage_tile<32>(Abase_l + k0, DD, ldsAl[cur ^ 1], t);
            stage_tile<32>(Bbase_h + k0, DD, ldsBh[cur ^ 1], t);
            stage_tile<32>(Bbase_l + k0, DD, ldsBl[cur ^ 1], t);
        }
        bf16x8 ah[4], al[4], bh[4], bl[4];
#pragma unroll
        for (int f = 0; f < 4; ++f) {
            ah[f] = ldsfrag<32>(ldsAh[cur], wr + f * 16, 0, lane);
            al[f] = ldsfrag<32>(ldsAl[cur], wr + f * 16, 0, lane);
            bh[f] = ldsfrag<32>(ldsBh[cur], wc + f * 16, 0, lane);
            bl[f] = ldsfrag<32>(ldsBl[cur], wc + f * 16, 0, lane);
        }
#pragma unroll
        for (int m = 0; m < 4; ++m)
#pragma unroll
            for (int n = 0; n < 4; ++n) {
                acc[m][n] = MFMA(ah[m], bh[n], acc[m][n]);
                acc[m][n] = MFMA(ah[m], bl[n], acc[m][n]);
                acc[m][n] = MFMA(al[m], bh[n], acc[m][n]);
            }
        __syncthreads();
    }
    int r4 = (lane >> 4) << 2, cl = lane & 15;
#pragma unroll
    for (int m = 0; m < 4; ++m)
#pragma unroll
        for (int n = 0; n < 4; ++n) {
            int col = col0 + wc + n * 16 + cl;
            float bv = bias[col];
#pragma unroll
            for (int r = 0; r < 4; ++r) {
                int row = row0 + wr + m * 16 + r4 + r;
                float v = acc[m][n][r] + bv;
                unsigned short hi = f2bf(v);
                size_t o = (size_t)row * AA + col;
                Oh[o] = hi;
                Ol[o] = f2bf(v - bf2f(hi));
            }
        }
}

// ---------- scores: S[b][n][m] = sum_a Q[n][a] K[m][a]  (f32), 2-phase dbuf ----------
__global__ __launch_bounds__(256) void k_scores(const unsigned short* __restrict__ Qh,
                                                const unsigned short* __restrict__ Ql,
                                                const unsigned short* __restrict__ Kh,
                                                const unsigned short* __restrict__ Kl,
                                                float* __restrict__ S) {
    __shared__ unsigned short ldsAh[2][128 * 32], ldsAl[2][128 * 32];
    __shared__ unsigned short ldsBh[2][128 * 32], ldsBl[2][128 * 32];
    int t = threadIdx.x, lane = t & 63, wave = t >> 6;
    int b = blockIdx.z;
    int nrow0 = blockIdx.x * 128;
    int mcol0 = blockIdx.y * 128;
    const unsigned short* Qhb = Qh + (size_t)(b * NN + nrow0) * AA;
    const unsigned short* Qlb = Ql + (size_t)(b * NN + nrow0) * AA;
    const unsigned short* Khb = Kh + (size_t)(b * NN + mcol0) * AA;
    const unsigned short* Klb = Kl + (size_t)(b * NN + mcol0) * AA;
    int wr = (wave >> 1) * 64, wc = (wave & 1) * 64;
    f32x4 acc[4][4] = {};
    stage_tile<32>(Qhb, AA, ldsAh[0], t);
    stage_tile<32>(Qlb, AA, ldsAl[0], t);
    stage_tile<32>(Khb, AA, ldsBh[0], t);
    stage_tile<32>(Klb, AA, ldsBl[0], t);
    __syncthreads();
    constexpr int NT = AA / 32;
    for (int tt = 0; tt < NT; ++tt) {
        int cur = tt & 1;
        if (tt + 1 < NT) {
            int k0 = (tt + 1) * 32;
            stage_tile<32>(Qhb + k0, AA, ldsAh[cur ^ 1], t);
            stage_tile<32>(Qlb + k0, AA, ldsAl[cur ^ 1], t);
            stage_tile<32>(Khb + k0, AA, ldsBh[cur ^ 1], t);
            stage_tile<32>(Klb + k0, AA, ldsBl[cur ^ 1], t);
        }
        bf16x8 ah[4], al[4], bh[4], bl[4];
#pragma unroll
        for (int f = 0; f < 4; ++f) {
            ah[f] = ldsfrag<32>(ldsAh[cur], wr + f * 16, 0, lane);
            al[f] = ldsfrag<32>(ldsAl[cur], wr + f * 16, 0, lane);
            bh[f] = ldsfrag<32>(ldsBh[cur], wc + f * 16, 0, lane);
            bl[f] = ldsfrag<32>(ldsBl[cur], wc + f * 16, 0, lane);
        }
#pragma unroll
        for (int m = 0; m < 4; ++m)
#pragma unroll
            for (int n = 0; n < 4; ++n) {
                acc[m][n] = MFMA(ah[m], bh[n], acc[m][n]);
                acc[m][n] = MFMA(ah[m], bl[n], acc[m][n]);
                acc[m][n] = MFMA(al[m], bh[n], acc[m][n]);
            }
        __syncthreads();
    }
    int r4 = (lane >> 4) << 2, cl = lane & 15;
#pragma unroll
    for (int m = 0; m < 4; ++m)
#pragma unroll
        for (int n = 0; n < 4; ++n) {
#pragma unroll
            for (int r = 0; r < 4; ++r) {
                int nrow = nrow0 + wr + m * 16 + r4 + r;
                int mcol = mcol0 + wc + n * 16 + cl;
                S[((size_t)(b * NN + nrow)) * NN + mcol] = acc[m][n][r];
            }
        }
}

// ---------- softmax rows of S (+mask), write P bf16 in-place ----------
__global__ __launch_bounds__(256) void k_softmax(float* __restrict__ S,
                                                 const float* __restrict__ mask) {
    int row = blockIdx.x;          // b*NN + n
    int b = row >> 11;
    float* srow = S + (size_t)row * NN;
    const float* mrow = mask + (size_t)b * NN;
    int t = threadIdx.x;
    float v[8];
    float mx = -3.0e38f;
#pragma unroll
    for (int i = 0; i < 8; ++i) {
        int m = t + i * 256;
        v[i] = srow[m] + mrow[m];
        mx = fmaxf(mx, v[i]);
    }
#pragma unroll
    for (int off = 32; off; off >>= 1) mx = fmaxf(mx, __shfl_xor(mx, off));
    __shared__ float redm[4], reds[4];
    int lane = t & 63, wave = t >> 6;
    if (lane == 0) redm[wave] = mx;
    __syncthreads();
    mx = fmaxf(fmaxf(redm[0], redm[1]), fmaxf(redm[2], redm[3]));
    float s = 0.f;
#pragma unroll
    for (int i = 0; i < 8; ++i) { v[i] = __expf(v[i] - mx); s += v[i]; }
#pragma unroll
    for (int off = 32; off; off >>= 1) s += __shfl_xor(s, off);
    if (lane == 0) reds[wave] = s;
    __syncthreads();
    s = reds[0] + reds[1] + reds[2] + reds[3];
    float inv = 1.0f / s;
    unsigned short* prow = (unsigned short*)srow;   // all reads done pre-barrier
#pragma unroll
    for (int i = 0; i < 8; ++i) {
        int m = t + i * 256;
        prow[m] = f2bf(v[i] * inv);
    }
}

// ---------- PV: out[b][n][d] = sum_m P[n][m] * X[b][m][d], 2-phase dbuf ----------
__global__ __launch_bounds__(256) void k_pv(const float* __restrict__ Sbuf,
                                            const unsigned short* __restrict__ XT,
                                            float* __restrict__ Out) {
    __shared__ unsigned short ldsA[2][128 * 64], ldsB[2][128 * 64];
    int t = threadIdx.x, lane = t & 63, wave = t >> 6;
    int b = blockIdx.z;
    int nrow0 = blockIdx.x * 128;
    int d0    = blockIdx.y * 128;
    const unsigned short* P = (const unsigned short*)Sbuf;  // row pitch 2*NN ushorts
    const unsigned short* Pb = P + (size_t)(b * NN + nrow0) * (NN * 2);
    const unsigned short* XTb = XT + (size_t)b * DD * NN + (size_t)d0 * NN;
    int wr = (wave >> 1) * 64, wc = (wave & 1) * 64;
    f32x4 acc[4][4] = {};
    stage_tile<64>(Pb, NN * 2, ldsA[0], t);
    stage_tile<64>(XTb, NN, ldsB[0], t);
    __syncthreads();
    constexpr int NT = NN / 64;
    for (int tt = 0; tt < NT; ++tt) {
        int cur = tt & 1;
        if (tt + 1 < NT) {
            int m0 = (tt + 1) * 64;
            stage_tile<64>(Pb + m0, NN * 2, ldsA[cur ^ 1], t);
            stage_tile<64>(XTb + m0, NN, ldsB[cur ^ 1], t);
        }
        bf16x8 pa[2][4], vb[2][4];
#pragma unroll
        for (int ks = 0; ks < 2; ++ks)
#pragma unroll
            for (int f = 0; f < 4; ++f) {
                pa[ks][f] = ldsfrag<64>(ldsA[cur], wr + f * 16, ks, lane);
                vb[ks][f] = ldsfrag<64>(ldsB[cur], wc + f * 16, ks, lane);
            }
#pragma unroll
        for (int ks = 0; ks < 2; ++ks)
#pragma unroll
            for (int m = 0; m < 4; ++m)
#pragma unroll
                for (int n = 0; n < 4; ++n)
                    acc[m][n] = MFMA(pa[ks][m], vb[ks][n], acc[m][n]);
        __syncthreads();
    }
    int r4 = (lane >> 4) << 2, cl = lane & 15;
#pragma unroll
    for (int m = 0; m < 4; ++m)
#pragma unroll
        for (int n = 0; n < 4; ++n) {
#pragma unroll
            for (int r = 0; r < 4; ++r) {
                int row = b * NN + nrow0 + wr + m * 16 + r4 + r;
                int dc = d0 + wc + n * 16 + cl;
                Out[(size_t)row * DD + dc] = acc[m][n][r];
            }
        }
}

extern "C" void kernel_launch(void* const* d_in, const int* in_sizes, int n_in,
                              void* d_out, int out_size, void* d_ws, size_t ws_size,
                              hipStream_t stream) {
    const float* X    = (const float*)d_in[0];
    const float* mask = (const float*)d_in[1];
    const float* Wq   = (const float*)d_in[2];
    const float* bq   = (const float*)d_in[3];
    const float* Wk   = (const float*)d_in[4];
    const float* bk   = (const float*)d_in[5];
    float* Out = (float*)d_out;

    unsigned short* Xh   = (unsigned short*)d_ws;
    unsigned short* Xl   = Xh + (size_t)BB * NN * DD;
    unsigned short* XT   = Xl + (size_t)BB * NN * DD;
    unsigned short* WqTh = XT + (size_t)BB * NN * DD;
    unsigned short* WqTl = WqTh + (size_t)AA * DD;
    unsigned short* WkTh = WqTl + (size_t)AA * DD;
    unsigned short* WkTl = WkTh + (size_t)AA * DD;
    unsigned short* Qh   = WkTl + (size_t)AA * DD;
    unsigned short* Ql   = Qh + (size_t)BB * NN * AA;
    unsigned short* Kh   = Ql + (size_t)BB * NN * AA;
    unsigned short* Kl   = Kh + (size_t)BB * NN * AA;
    float* S = (float*)(Kl + (size_t)BB * NN * AA);

    k_prep<<<dim3(NN / 64, DD / 64, BB), 256, 0, stream>>>(X, Xh, Xl, XT);
    k_wsplit<<<dim3((AA * DD) / 256), 256, 0, stream>>>(Wq, WqTh, WqTl);
    k_wsplit<<<dim3((AA * DD) / 256), 256, 0, stream>>>(Wk, WkTh, WkTl);

    k_proj<<<dim3((BB * NN) / 128, 4), 256, 0, stream>>>(Xh, Xl, WqTh, WqTl, WkTh, WkTl,
                                                         bq, bk, Qh, Ql, Kh, Kl);

    k_scores<<<dim3(NN / 128, NN / 128, BB), 256, 0, stream>>>(Qh, Ql, Kh, Kl, S);
    k_softmax<<<dim3(BB * NN), 256, 0, stream>>>(S, mask);
    k_pv<<<dim3(NN / 128, DD / 128, BB), 256, 0, stream>>>(S, XT, Out);
}

// Round 4
// 161.901 us; speedup vs baseline: 2.2833x; 1.0451x over previous
//
#include <hip/hip_runtime.h>
#include <hip/hip_bf16.h>

// GlobalAttention: B=4, N=2048, D=1024, A=256, f32 in/out.
// out = softmax( (X Wq + bq)(X Wk + bk)^T + mask ) X
// R4: counted-vmcnt double-buffer pipeline (T4): raw s_barrier (no compiler
// vmcnt(0) drain) + "s_waitcnt vmcnt(8)" so next-tile global_load_lds stay in
// flight across the barrier. Both-sides XOR slot swizzle. Split-bf16 x3 for
// proj+scores, bf16 PV. Fused prep.

#define BB 4
#define NN 2048
#define DD 1024
#define AA 256

using bf16x8 = __attribute__((ext_vector_type(8))) __bf16;
using f32x4  = __attribute__((ext_vector_type(4))) float;

#define MFMA(a, b, c) __builtin_amdgcn_mfma_f32_16x16x32_bf16(a, b, c, 0, 0, 0)

#define VMCNT(n) asm volatile("s_waitcnt vmcnt(" #n ")" ::: "memory")
#define CFENCE() asm volatile("" ::: "memory")
#define BARRIER() __builtin_amdgcn_s_barrier()

static __device__ __forceinline__ unsigned short f2bf(float x) {
    union { float f; unsigned int u; } c; c.f = x;
    unsigned int u = c.u;
    u += 0x7fffu + ((u >> 16) & 1u);   // round-to-nearest-even
    return (unsigned short)(u >> 16);
}
static __device__ __forceinline__ float bf2f(unsigned short h) {
    union { unsigned int u; float f; } c; c.u = ((unsigned int)h) << 16;
    return c.f;
}

// ---- swizzle: slot' = slot ^ swz(row); involution on stage-src AND ds_read ----
template<int SLOTS>
static __device__ __forceinline__ int swz(int r) {
    return (SLOTS == 4) ? ((r >> 1) & 3) : (r & 7);
}

// Stage a [128][BK] bf16 tile into LDS; linear LDS dest, swizzle on global src slot.
template<int BK>
static __device__ __forceinline__ void stage_tile(const unsigned short* __restrict__ g,
                                                  int pitch, unsigned short* lds, int t) {
    constexpr int SLOTS = BK / 8;
    constexpr int ISSUES = (128 * SLOTS) / 256;
#pragma unroll
    for (int i = 0; i < ISSUES; ++i) {
        int tt = t + i * 256;
        int row = tt / SLOTS;
        int slot = (tt % SLOTS) ^ swz<SLOTS>(row);
        const char* src = (const char*)(g + (size_t)row * pitch) + slot * 16;
        __builtin_amdgcn_global_load_lds((const unsigned int*)src,
                                         (unsigned int*)((char*)lds + (size_t)tt * 16),
                                         16, 0, 0);
    }
}

template<int BK>
static __device__ __forceinline__ bf16x8 ldsfrag(const unsigned short* lds, int row,
                                                 int ks, int lane) {
    constexpr int SLOTS = BK / 8;
    int r = row + (lane & 15);
    int slot = (ks * 4 + (lane >> 4)) ^ swz<SLOTS>(r);
    return *reinterpret_cast<const bf16x8*>((const char*)lds + (size_t)r * (BK * 2) + slot * 16);
}

// ---------- fused prep: X -> Xh, Xl (row-major) and XT bf16 [B][D][N] ----------
__global__ __launch_bounds__(256) void k_prep(const float* __restrict__ X,
                                              unsigned short* __restrict__ Xh,
                                              unsigned short* __restrict__ Xl,
                                              unsigned short* __restrict__ XT) {
    __shared__ unsigned short tile[64][65];   // [d][n], hi values
    int t = threadIdx.x;
    int n0 = blockIdx.x * 64, d0 = blockIdx.y * 64;
    const float* Xb = X + (size_t)blockIdx.z * NN * DD;
    unsigned short* Xhb = Xh + (size_t)blockIdx.z * NN * DD;
    unsigned short* Xlb = Xl + (size_t)blockIdx.z * NN * DD;
    unsigned short* XTb = XT + (size_t)blockIdx.z * DD * NN;
    int r = t >> 4, c4 = (t & 15) * 4;
#pragma unroll
    for (int i = 0; i < 4; ++i) {
        int row = r + 16 * i;
        float4 v = *reinterpret_cast<const float4*>(Xb + (size_t)(n0 + row) * DD + d0 + c4);
        ushort4 h, l;
        h.x = f2bf(v.x); l.x = f2bf(v.x - bf2f(h.x));
        h.y = f2bf(v.y); l.y = f2bf(v.y - bf2f(h.y));
        h.z = f2bf(v.z); l.z = f2bf(v.z - bf2f(h.z));
        h.w = f2bf(v.w); l.w = f2bf(v.w - bf2f(h.w));
        *reinterpret_cast<ushort4*>(Xhb + (size_t)(n0 + row) * DD + d0 + c4) = h;
        *reinterpret_cast<ushort4*>(Xlb + (size_t)(n0 + row) * DD + d0 + c4) = l;
        tile[c4 + 0][row] = h.x;
        tile[c4 + 1][row] = h.y;
        tile[c4 + 2][row] = h.z;
        tile[c4 + 3][row] = h.w;
    }
    __syncthreads();
    int j = t & 63, i4 = t >> 6;
#pragma unroll
    for (int jj = i4; jj < 64; jj += 4)
        XTb[(size_t)(d0 + jj) * NN + n0 + j] = tile[jj][j];
}

// ---------- prep: W[D][A] -> WT hi/lo bf16 [A][D] ----------
__global__ __launch_bounds__(256) void k_wsplit(const float* __restrict__ W,
                                                unsigned short* __restrict__ WTh,
                                                unsigned short* __restrict__ WTl) {
    int idx = blockIdx.x * 256 + threadIdx.x;
    int a = idx >> 10;
    int d = idx & (DD - 1);
    float w = W[(size_t)d * AA + a];
    unsigned short hi = f2bf(w);
    WTh[idx] = hi;
    WTl[idx] = f2bf(w - bf2f(hi));
}

// ---------- fused proj: {Q,K} = X W{q,k} + b -> split bf16 [B*N][A] ----------
__global__ __launch_bounds__(256) void k_proj(const unsigned short* __restrict__ Xh,
                                              const unsigned short* __restrict__ Xl,
                                              const unsigned short* __restrict__ WqTh,
                                              const unsigned short* __restrict__ WqTl,
                                              const unsigned short* __restrict__ WkTh,
                                              const unsigned short* __restrict__ WkTl,
                                              const float* __restrict__ bq,
                                              const float* __restrict__ bk,
                                              unsigned short* __restrict__ Qh,
                                              unsigned short* __restrict__ Ql,
                                              unsigned short* __restrict__ Kh,
                                              unsigned short* __restrict__ Kl) {
    __shared__ unsigned short ldsAh[2][128 * 32], ldsAl[2][128 * 32];
    __shared__ unsigned short ldsBh[2][128 * 32], ldsBl[2][128 * 32];
    int t = threadIdx.x, lane = t & 63, wave = t >> 6;
    int row0 = blockIdx.x * 128;
    int which = blockIdx.y >> 1;
    int col0 = (blockIdx.y & 1) * 128;
    const unsigned short* BTh = which ? WkTh : WqTh;
    const unsigned short* BTl = which ? WkTl : WqTl;
    const float* bias = which ? bk : bq;
    unsigned short* Oh = which ? Kh : Qh;
    unsigned short* Ol = which ? Kl : Ql;
    const unsigned short* Abase_h = Xh + (size_t)row0 * DD;
    const unsigned short* Abase_l = Xl + (size_t)row0 * DD;
    const unsigned short* Bbase_h = BTh + (size_t)col0 * DD;
    const unsigned short* Bbase_l = BTl + (size_t)col0 * DD;
    int wr = (wave >> 1) * 64, wc = (wave & 1) * 64;
    f32x4 acc[4][4] = {};
    stage_tile<32>(Abase_h, DD, ldsAh[0], t);
    stage_tile<32>(Abase_l, DD, ldsAl[0], t);
    stage_tile<32>(Bbase_h, DD, ldsBh[0], t);
    stage_tile<32>(Bbase_l, DD, ldsBl[0], t);
    constexpr int NT = DD / 32;
    for (int tt = 0; tt < NT; ++tt) {
        int cur = tt & 1;
        CFENCE();
        BARRIER();                      // iter t-1 reads of buf[cur^1] done
        if (tt + 1 < NT) {
            int k0 = (tt + 1) * 32;
            stage_tile<32>(Abase_h + k0, DD, ldsAh[cur ^ 1], t);
            stage_tile<32>(Abase_l + k0, DD, ldsAl[cur ^ 1], t);
            stage_tile<32>(Bbase_h + k0, DD, ldsBh[cur ^ 1], t);
            stage_tile<32>(Bbase_l + k0, DD, ldsBl[cur ^ 1], t);
            VMCNT(8);                   // stage(tt) landed; tt+1's 8 in flight
        } else {
            VMCNT(0);
        }
        BARRIER();                      // everyone's stage(tt) landed
        CFENCE();
        bf16x8 ah[4], al[4], bh[4], bl[4];
#pragma unroll
        for (int f = 0; f < 4; ++f) {
            ah[f] = ldsfrag<32>(ldsAh[cur], wr + f * 16, 0, lane);
            al[f] = ldsfrag<32>(ldsAl[cur], wr + f * 16, 0, lane);
            bh[f] = ldsfrag<32>(ldsBh[cur], wc + f * 16, 0, lane);
            bl[f] = ldsfrag<32>(ldsBl[cur], wc + f * 16, 0, lane);
        }
#pragma unroll
        for (int m = 0; m < 4; ++m)
#pragma unroll
            for (int n = 0; n < 4; ++n) {
                acc[m][n] = MFMA(ah[m], bh[n], acc[m][n]);
                acc[m][n] = MFMA(ah[m], bl[n], acc[m][n]);
                acc[m][n] = MFMA(al[m], bh[n], acc[m][n]);
            }
    }
    int r4 = (lane >> 4) << 2, cl = lane & 15;
#pragma unroll
    for (int m = 0; m < 4; ++m)
#pragma unroll
        for (int n = 0; n < 4; ++n) {
            int col = col0 + wc + n * 16 + cl;
            float bv = bias[col];
#pragma unroll
            for (int r = 0; r < 4; ++r) {
                int row = row0 + wr + m * 16 + r4 + r;
                float v = acc[m][n][r] + bv;
                unsigned short hi = f2bf(v);
                size_t o = (size_t)row * AA + col;
                Oh[o] = hi;
                Ol[o] = f2bf(v - bf2f(hi));
            }
        }
}

// ---------- scores: S[b][n][m] = sum_a Q[n][a] K[m][a]  (f32) ----------
__global__ __launch_bounds__(256) void k_scores(const unsigned short* __restrict__ Qh,
                                                const unsigned short* __restrict__ Ql,
                                                const unsigned short* __restrict__ Kh,
                                                const unsigned short* __restrict__ Kl,
                                                float* __restrict__ S) {
    __shared__ unsigned short ldsAh[2][128 * 32], ldsAl[2][128 * 32];
    __shared__ unsigned short ldsBh[2][128 * 32], ldsBl[2][128 * 32];
    int t = threadIdx.x, lane = t & 63, wave = t >> 6;
    int b = blockIdx.z;
    int nrow0 = blockIdx.x * 128;
    int mcol0 = blockIdx.y * 128;
    const unsigned short* Qhb = Qh + (size_t)(b * NN + nrow0) * AA;
    const unsigned short* Qlb = Ql + (size_t)(b * NN + nrow0) * AA;
    const unsigned short* Khb = Kh + (size_t)(b * NN + mcol0) * AA;
    const unsigned short* Klb = Kl + (size_t)(b * NN + mcol0) * AA;
    int wr = (wave >> 1) * 64, wc = (wave & 1) * 64;
    f32x4 acc[4][4] = {};
    stage_tile<32>(Qhb, AA, ldsAh[0], t);
    stage_tile<32>(Qlb, AA, ldsAl[0], t);
    stage_tile<32>(Khb, AA, ldsBh[0], t);
    stage_tile<32>(Klb, AA, ldsBl[0], t);
    constexpr int NT = AA / 32;
    for (int tt = 0; tt < NT; ++tt) {
        int cur = tt & 1;
        CFENCE();
        BARRIER();
        if (tt + 1 < NT) {
            int k0 = (tt + 1) * 32;
            stage_tile<32>(Qhb + k0, AA, ldsAh[cur ^ 1], t);
            stage_tile<32>(Qlb + k0, AA, ldsAl[cur ^ 1], t);
            stage_tile<32>(Khb + k0, AA, ldsBh[cur ^ 1], t);
            stage_tile<32>(Klb + k0, AA, ldsBl[cur ^ 1], t);
            VMCNT(8);
        } else {
            VMCNT(0);
        }
        BARRIER();
        CFENCE();
        bf16x8 ah[4], al[4], bh[4], bl[4];
#pragma unroll
        for (int f = 0; f < 4; ++f) {
            ah[f] = ldsfrag<32>(ldsAh[cur], wr + f * 16, 0, lane);
            al[f] = ldsfrag<32>(ldsAl[cur], wr + f * 16, 0, lane);
            bh[f] = ldsfrag<32>(ldsBh[cur], wc + f * 16, 0, lane);
            bl[f] = ldsfrag<32>(ldsBl[cur], wc + f * 16, 0, lane);
        }
#pragma unroll
        for (int m = 0; m < 4; ++m)
#pragma unroll
            for (int n = 0; n < 4; ++n) {
                acc[m][n] = MFMA(ah[m], bh[n], acc[m][n]);
                acc[m][n] = MFMA(ah[m], bl[n], acc[m][n]);
                acc[m][n] = MFMA(al[m], bh[n], acc[m][n]);
            }
    }
    int r4 = (lane >> 4) << 2, cl = lane & 15;
#pragma unroll
    for (int m = 0; m < 4; ++m)
#pragma unroll
        for (int n = 0; n < 4; ++n) {
#pragma unroll
            for (int r = 0; r < 4; ++r) {
                int nrow = nrow0 + wr + m * 16 + r4 + r;
                int mcol = mcol0 + wc + n * 16 + cl;
                S[((size_t)(b * NN + nrow)) * NN + mcol] = acc[m][n][r];
            }
        }
}

// ---------- softmax rows of S (+mask), write P bf16 in-place ----------
__global__ __launch_bounds__(256) void k_softmax(float* __restrict__ S,
                                                 const float* __restrict__ mask) {
    int row = blockIdx.x;          // b*NN + n
    int b = row >> 11;
    float* srow = S + (size_t)row * NN;
    const float* mrow = mask + (size_t)b * NN;
    int t = threadIdx.x;
    float v[8];
    float mx = -3.0e38f;
#pragma unroll
    for (int i = 0; i < 8; ++i) {
        int m = t + i * 256;
        v[i] = srow[m] + mrow[m];
        mx = fmaxf(mx, v[i]);
    }
#pragma unroll
    for (int off = 32; off; off >>= 1) mx = fmaxf(mx, __shfl_xor(mx, off));
    __shared__ float redm[4], reds[4];
    int lane = t & 63, wave = t >> 6;
    if (lane == 0) redm[wave] = mx;
    __syncthreads();
    mx = fmaxf(fmaxf(redm[0], redm[1]), fmaxf(redm[2], redm[3]));
    float s = 0.f;
#pragma unroll
    for (int i = 0; i < 8; ++i) { v[i] = __expf(v[i] - mx); s += v[i]; }
#pragma unroll
    for (int off = 32; off; off >>= 1) s += __shfl_xor(s, off);
    if (lane == 0) reds[wave] = s;
    __syncthreads();
    s = reds[0] + reds[1] + reds[2] + reds[3];
    float inv = 1.0f / s;
    unsigned short* prow = (unsigned short*)srow;   // all reads done pre-barrier
#pragma unroll
    for (int i = 0; i < 8; ++i) {
        int m = t + i * 256;
        prow[m] = f2bf(v[i] * inv);
    }
}

// ---------- PV: out[b][n][d] = sum_m P[n][m] * X[b][m][d] ----------
__global__ __launch_bounds__(256) void k_pv(const float* __restrict__ Sbuf,
                                            const unsigned short* __restrict__ XT,
                                            float* __restrict__ Out) {
    __shared__ unsigned short ldsA[2][128 * 64], ldsB[2][128 * 64];
    int t = threadIdx.x, lane = t & 63, wave = t >> 6;
    int b = blockIdx.z;
    int nrow0 = blockIdx.x * 128;
    int d0    = blockIdx.y * 128;
    const unsigned short* P = (const unsigned short*)Sbuf;  // row pitch 2*NN ushorts
    const unsigned short* Pb = P + (size_t)(b * NN + nrow0) * (NN * 2);
    const unsigned short* XTb = XT + (size_t)b * DD * NN + (size_t)d0 * NN;
    int wr = (wave >> 1) * 64, wc = (wave & 1) * 64;
    f32x4 acc[4][4] = {};
    stage_tile<64>(Pb, NN * 2, ldsA[0], t);
    stage_tile<64>(XTb, NN, ldsB[0], t);
    constexpr int NT = NN / 64;
    for (int tt = 0; tt < NT; ++tt) {
        int cur = tt & 1;
        CFENCE();
        BARRIER();
        if (tt + 1 < NT) {
            int m0 = (tt + 1) * 64;
            stage_tile<64>(Pb + m0, NN * 2, ldsA[cur ^ 1], t);
            stage_tile<64>(XTb + m0, NN, ldsB[cur ^ 1], t);
            VMCNT(8);
        } else {
            VMCNT(0);
        }
        BARRIER();
        CFENCE();
        bf16x8 pa[2][4], vb[2][4];
#pragma unroll
        for (int ks = 0; ks < 2; ++ks)
#pragma unroll
            for (int f = 0; f < 4; ++f) {
                pa[ks][f] = ldsfrag<64>(ldsA[cur], wr + f * 16, ks, lane);
                vb[ks][f] = ldsfrag<64>(ldsB[cur], wc + f * 16, ks, lane);
            }
#pragma unroll
        for (int ks = 0; ks < 2; ++ks)
#pragma unroll
            for (int m = 0; m < 4; ++m)
#pragma unroll
                for (int n = 0; n < 4; ++n)
                    acc[m][n] = MFMA(pa[ks][m], vb[ks][n], acc[m][n]);
    }
    int r4 = (lane >> 4) << 2, cl = lane & 15;
#pragma unroll
    for (int m = 0; m < 4; ++m)
#pragma unroll
        for (int n = 0; n < 4; ++n) {
#pragma unroll
            for (int r = 0; r < 4; ++r) {
                int row = b * NN + nrow0 + wr + m * 16 + r4 + r;
                int dc = d0 + wc + n * 16 + cl;
                Out[(size_t)row * DD + dc] = acc[m][n][r];
            }
        }
}

extern "C" void kernel_launch(void* const* d_in, const int* in_sizes, int n_in,
                              void* d_out, int out_size, void* d_ws, size_t ws_size,
                              hipStream_t stream) {
    const float* X    = (const float*)d_in[0];
    const float* mask = (const float*)d_in[1];
    const float* Wq   = (const float*)d_in[2];
    const float* bq   = (const float*)d_in[3];
    const float* Wk   = (const float*)d_in[4];
    const float* bk   = (const float*)d_in[5];
    float* Out = (float*)d_out;

    unsigned short* Xh   = (unsigned short*)d_ws;
    unsigned short* Xl   = Xh + (size_t)BB * NN * DD;
    unsigned short* XT   = Xl + (size_t)BB * NN * DD;
    unsigned short* WqTh = XT + (size_t)BB * NN * DD;
    unsigned short* WqTl = WqTh + (size_t)AA * DD;
    unsigned short* WkTh = WqTl + (size_t)AA * DD;
    unsigned short* WkTl = WkTh + (size_t)AA * DD;
    unsigned short* Qh   = WkTl + (size_t)AA * DD;
    unsigned short* Ql   = Qh + (size_t)BB * NN * AA;
    unsigned short* Kh   = Ql + (size_t)BB * NN * AA;
    unsigned short* Kl   = Kh + (size_t)BB * NN * AA;
    float* S = (float*)(Kl + (size_t)BB * NN * AA);

    k_prep<<<dim3(NN / 64, DD / 64, BB), 256, 0, stream>>>(X, Xh, Xl, XT);
    k_wsplit<<<dim3((AA * DD) / 256), 256, 0, stream>>>(Wq, WqTh, WqTl);
    k_wsplit<<<dim3((AA * DD) / 256), 256, 0, stream>>>(Wk, WkTh, WkTl);

    k_proj<<<dim3((BB * NN) / 128, 4), 256, 0, stream>>>(Xh, Xl, WqTh, WqTl, WkTh, WkTl,
                                                         bq, bk, Qh, Ql, Kh, Kl);

    k_scores<<<dim3(NN / 128, NN / 128, BB), 256, 0, stream>>>(Qh, Ql, Kh, Kl, S);
    k_softmax<<<dim3(BB * NN), 256, 0, stream>>>(S, mask);
    k_pv<<<dim3(NN / 128, DD / 128, BB), 256, 0, stream>>>(S, XT, Out);
}

// Round 6
// 153.385 us; speedup vs baseline: 2.4101x; 1.0555x over previous
//
#include <hip/hip_runtime.h>
#include <hip/hip_bf16.h>

// GlobalAttention: B=4, N=2048, D=1024, A=256, f32 in/out.
// out = softmax( (X Wq + bq)(X Wk + bk)^T + mask ) X
// R6 (= R5 + compile fixes): k_pv -> 8-wave 128x256 tile, BK=64, 3-buffer
// depth-2 prefetch, 4-phase interleave, setprio (T3+T4+T5). k_proj -> 64x128
// tile (3 blocks/CU). Vectorized softmax. Split-bf16 x3 proj+scores, bf16 PV.
// Fixes vs R5: no LDS-pointer arrays (addrspacecast static-init error);
// no static guard around hipFuncSetAttribute.

#define BB 4
#define NN 2048
#define DD 1024
#define AA 256

using bf16x8 = __attribute__((ext_vector_type(8))) __bf16;
using f32x4  = __attribute__((ext_vector_type(4))) float;

#define MFMA(a, b, c) __builtin_amdgcn_mfma_f32_16x16x32_bf16(a, b, c, 0, 0, 0)

#define VMCNT(n) asm volatile("s_waitcnt vmcnt(" #n ")" ::: "memory")
#define CFENCE() asm volatile("" ::: "memory")
#define BARRIER() __builtin_amdgcn_s_barrier()

static __device__ __forceinline__ unsigned short f2bf(float x) {
    union { float f; unsigned int u; } c; c.f = x;
    unsigned int u = c.u;
    u += 0x7fffu + ((u >> 16) & 1u);   // round-to-nearest-even
    return (unsigned short)(u >> 16);
}
static __device__ __forceinline__ float bf2f(unsigned short h) {
    union { unsigned int u; float f; } c; c.u = ((unsigned int)h) << 16;
    return c.f;
}

// ---- swizzle: slot' = slot ^ swz(row); involution on stage-src AND ds_read ----
template<int SLOTS>
static __device__ __forceinline__ int swz(int r) {
    return (SLOTS == 4) ? ((r >> 1) & 3) : (r & 7);
}

// Stage issues [I0,I1) of a [ROWS][BK] bf16 tile into LDS (linear dest,
// swizzle applied on the GLOBAL source slot).
template<int ROWS, int BK, int THREADS, int I0, int I1>
static __device__ __forceinline__ void stage_part(const unsigned short* __restrict__ g,
                                                  int pitch, unsigned short* lds, int t) {
    constexpr int SLOTS = BK / 8;
#pragma unroll
    for (int i = I0; i < I1; ++i) {
        int tt = t + i * THREADS;
        int row = tt / SLOTS;
        int slot = (tt % SLOTS) ^ swz<SLOTS>(row);
        const char* src = (const char*)(g + (size_t)row * pitch) + slot * 16;
        __builtin_amdgcn_global_load_lds((const unsigned int*)src,
                                         (unsigned int*)((char*)lds + (size_t)tt * 16),
                                         16, 0, 0);
    }
}

template<int BK>
static __device__ __forceinline__ bf16x8 ldsfrag(const unsigned short* lds, int row,
                                                 int ks, int lane) {
    constexpr int SLOTS = BK / 8;
    int r = row + (lane & 15);
    int slot = (ks * 4 + (lane >> 4)) ^ swz<SLOTS>(r);
    return *reinterpret_cast<const bf16x8*>((const char*)lds + (size_t)r * (BK * 2) + slot * 16);
}

// ---------- fused prep: X -> Xh, Xl (row-major) and XT bf16 [B][D][N] ----------
__global__ __launch_bounds__(256) void k_prep(const float* __restrict__ X,
                                              unsigned short* __restrict__ Xh,
                                              unsigned short* __restrict__ Xl,
                                              unsigned short* __restrict__ XT) {
    __shared__ unsigned short tile[64][65];   // [d][n], hi values
    int t = threadIdx.x;
    int n0 = blockIdx.x * 64, d0 = blockIdx.y * 64;
    const float* Xb = X + (size_t)blockIdx.z * NN * DD;
    unsigned short* Xhb = Xh + (size_t)blockIdx.z * NN * DD;
    unsigned short* Xlb = Xl + (size_t)blockIdx.z * NN * DD;
    unsigned short* XTb = XT + (size_t)blockIdx.z * DD * NN;
    int r = t >> 4, c4 = (t & 15) * 4;
#pragma unroll
    for (int i = 0; i < 4; ++i) {
        int row = r + 16 * i;
        float4 v = *reinterpret_cast<const float4*>(Xb + (size_t)(n0 + row) * DD + d0 + c4);
        ushort4 h, l;
        h.x = f2bf(v.x); l.x = f2bf(v.x - bf2f(h.x));
        h.y = f2bf(v.y); l.y = f2bf(v.y - bf2f(h.y));
        h.z = f2bf(v.z); l.z = f2bf(v.z - bf2f(h.z));
        h.w = f2bf(v.w); l.w = f2bf(v.w - bf2f(h.w));
        *reinterpret_cast<ushort4*>(Xhb + (size_t)(n0 + row) * DD + d0 + c4) = h;
        *reinterpret_cast<ushort4*>(Xlb + (size_t)(n0 + row) * DD + d0 + c4) = l;
        tile[c4 + 0][row] = h.x;
        tile[c4 + 1][row] = h.y;
        tile[c4 + 2][row] = h.z;
        tile[c4 + 3][row] = h.w;
    }
    __syncthreads();
    int j = t & 63, i4 = t >> 6;
#pragma unroll
    for (int jj = i4; jj < 64; jj += 4)
        XTb[(size_t)(d0 + jj) * NN + n0 + j] = tile[jj][j];
}

// ---------- prep: W[D][A] -> WT hi/lo bf16 [A][D] ----------
__global__ __launch_bounds__(256) void k_wsplit(const float* __restrict__ W,
                                                unsigned short* __restrict__ WTh,
                                                unsigned short* __restrict__ WTl) {
    int idx = blockIdx.x * 256 + threadIdx.x;
    int a = idx >> 10;
    int d = idx & (DD - 1);
    float w = W[(size_t)d * AA + a];
    unsigned short hi = f2bf(w);
    WTh[idx] = hi;
    WTl[idx] = f2bf(w - bf2f(hi));
}

// ---------- fused proj: {Q,K} = X W{q,k} + b -> split bf16 [B*N][A] ----------
// 64x128 tile, 4 waves of 64x32, 2-phase counted-vmcnt. grid (128, 4).
__global__ __launch_bounds__(256) void k_proj(const unsigned short* __restrict__ Xh,
                                              const unsigned short* __restrict__ Xl,
                                              const unsigned short* __restrict__ WqTh,
                                              const unsigned short* __restrict__ WqTl,
                                              const unsigned short* __restrict__ WkTh,
                                              const unsigned short* __restrict__ WkTl,
                                              const float* __restrict__ bq,
                                              const float* __restrict__ bk,
                                              unsigned short* __restrict__ Qh,
                                              unsigned short* __restrict__ Ql,
                                              unsigned short* __restrict__ Kh,
                                              unsigned short* __restrict__ Kl) {
    __shared__ unsigned short ldsAh[2][64 * 32], ldsAl[2][64 * 32];
    __shared__ unsigned short ldsBh[2][128 * 32], ldsBl[2][128 * 32];
    int t = threadIdx.x, lane = t & 63, wave = t >> 6;
    int row0 = blockIdx.x * 64;
    int which = blockIdx.y >> 1;
    int col0 = (blockIdx.y & 1) * 128;
    const unsigned short* BTh = which ? WkTh : WqTh;
    const unsigned short* BTl = which ? WkTl : WqTl;
    const float* bias = which ? bk : bq;
    unsigned short* Oh = which ? Kh : Qh;
    unsigned short* Ol = which ? Kl : Ql;
    const unsigned short* Abase_h = Xh + (size_t)row0 * DD;
    const unsigned short* Abase_l = Xl + (size_t)row0 * DD;
    const unsigned short* Bbase_h = BTh + (size_t)col0 * DD;
    const unsigned short* Bbase_l = BTl + (size_t)col0 * DD;
    int wc = wave * 32;
    f32x4 acc[4][2] = {};
    stage_part<64, 32, 256, 0, 1>(Abase_h, DD, ldsAh[0], t);
    stage_part<64, 32, 256, 0, 1>(Abase_l, DD, ldsAl[0], t);
    stage_part<128, 32, 256, 0, 2>(Bbase_h, DD, ldsBh[0], t);
    stage_part<128, 32, 256, 0, 2>(Bbase_l, DD, ldsBl[0], t);
    constexpr int NT = DD / 32;
    for (int tt = 0; tt < NT; ++tt) {
        int cur = tt & 1;
        CFENCE();
        BARRIER();                      // iter tt-1 reads of buf[cur^1] done
        if (tt + 1 < NT) {
            int k0 = (tt + 1) * 32;
            stage_part<64, 32, 256, 0, 1>(Abase_h + k0, DD, ldsAh[cur ^ 1], t);
            stage_part<64, 32, 256, 0, 1>(Abase_l + k0, DD, ldsAl[cur ^ 1], t);
            stage_part<128, 32, 256, 0, 2>(Bbase_h + k0, DD, ldsBh[cur ^ 1], t);
            stage_part<128, 32, 256, 0, 2>(Bbase_l + k0, DD, ldsBl[cur ^ 1], t);
            VMCNT(6);                   // stage(tt) landed; tt+1's 6 in flight
        } else {
            VMCNT(0);
        }
        BARRIER();
        CFENCE();
        bf16x8 ah[4], al[4], bh[2], bl[2];
#pragma unroll
        for (int f = 0; f < 4; ++f) {
            ah[f] = ldsfrag<32>(ldsAh[cur], f * 16, 0, lane);
            al[f] = ldsfrag<32>(ldsAl[cur], f * 16, 0, lane);
        }
#pragma unroll
        for (int n = 0; n < 2; ++n) {
            bh[n] = ldsfrag<32>(ldsBh[cur], wc + n * 16, 0, lane);
            bl[n] = ldsfrag<32>(ldsBl[cur], wc + n * 16, 0, lane);
        }
        __builtin_amdgcn_s_setprio(1);
#pragma unroll
        for (int m = 0; m < 4; ++m)
#pragma unroll
            for (int n = 0; n < 2; ++n) {
                acc[m][n] = MFMA(ah[m], bh[n], acc[m][n]);
                acc[m][n] = MFMA(ah[m], bl[n], acc[m][n]);
                acc[m][n] = MFMA(al[m], bh[n], acc[m][n]);
            }
        __builtin_amdgcn_s_setprio(0);
    }
    int r4 = (lane >> 4) << 2, cl = lane & 15;
#pragma unroll
    for (int m = 0; m < 4; ++m)
#pragma unroll
        for (int n = 0; n < 2; ++n) {
            int col = col0 + wc + n * 16 + cl;
            float bv = bias[col];
#pragma unroll
            for (int r = 0; r < 4; ++r) {
                int row = row0 + m * 16 + r4 + r;
                float v = acc[m][n][r] + bv;
                unsigned short hi = f2bf(v);
                size_t o = (size_t)row * AA + col;
                Oh[o] = hi;
                Ol[o] = f2bf(v - bf2f(hi));
            }
        }
}

// ---------- scores: S[b][n][m] = sum_a Q[n][a] K[m][a]  (f32) ----------
__global__ __launch_bounds__(256) void k_scores(const unsigned short* __restrict__ Qh,
                                                const unsigned short* __restrict__ Ql,
                                                const unsigned short* __restrict__ Kh,
                                                const unsigned short* __restrict__ Kl,
                                                float* __restrict__ S) {
    __shared__ unsigned short ldsAh[2][128 * 32], ldsAl[2][128 * 32];
    __shared__ unsigned short ldsBh[2][128 * 32], ldsBl[2][128 * 32];
    int t = threadIdx.x, lane = t & 63, wave = t >> 6;
    int b = blockIdx.z;
    int nrow0 = blockIdx.x * 128;
    int mcol0 = blockIdx.y * 128;
    const unsigned short* Qhb = Qh + (size_t)(b * NN + nrow0) * AA;
    const unsigned short* Qlb = Ql + (size_t)(b * NN + nrow0) * AA;
    const unsigned short* Khb = Kh + (size_t)(b * NN + mcol0) * AA;
    const unsigned short* Klb = Kl + (size_t)(b * NN + mcol0) * AA;
    int wr = (wave >> 1) * 64, wc = (wave & 1) * 64;
    f32x4 acc[4][4] = {};
    stage_part<128, 32, 256, 0, 2>(Qhb, AA, ldsAh[0], t);
    stage_part<128, 32, 256, 0, 2>(Qlb, AA, ldsAl[0], t);
    stage_part<128, 32, 256, 0, 2>(Khb, AA, ldsBh[0], t);
    stage_part<128, 32, 256, 0, 2>(Klb, AA, ldsBl[0], t);
    constexpr int NT = AA / 32;
    for (int tt = 0; tt < NT; ++tt) {
        int cur = tt & 1;
        CFENCE();
        BARRIER();
        if (tt + 1 < NT) {
            int k0 = (tt + 1) * 32;
            stage_part<128, 32, 256, 0, 2>(Qhb + k0, AA, ldsAh[cur ^ 1], t);
            stage_part<128, 32, 256, 0, 2>(Qlb + k0, AA, ldsAl[cur ^ 1], t);
            stage_part<128, 32, 256, 0, 2>(Khb + k0, AA, ldsBh[cur ^ 1], t);
            stage_part<128, 32, 256, 0, 2>(Klb + k0, AA, ldsBl[cur ^ 1], t);
            VMCNT(8);
        } else {
            VMCNT(0);
        }
        BARRIER();
        CFENCE();
        bf16x8 ah[4], al[4], bh[4], bl[4];
#pragma unroll
        for (int f = 0; f < 4; ++f) {
            ah[f] = ldsfrag<32>(ldsAh[cur], wr + f * 16, 0, lane);
            al[f] = ldsfrag<32>(ldsAl[cur], wr + f * 16, 0, lane);
            bh[f] = ldsfrag<32>(ldsBh[cur], wc + f * 16, 0, lane);
            bl[f] = ldsfrag<32>(ldsBl[cur], wc + f * 16, 0, lane);
        }
        __builtin_amdgcn_s_setprio(1);
#pragma unroll
        for (int m = 0; m < 4; ++m)
#pragma unroll
            for (int n = 0; n < 4; ++n) {
                acc[m][n] = MFMA(ah[m], bh[n], acc[m][n]);
                acc[m][n] = MFMA(ah[m], bl[n], acc[m][n]);
                acc[m][n] = MFMA(al[m], bh[n], acc[m][n]);
            }
        __builtin_amdgcn_s_setprio(0);
    }
    int r4 = (lane >> 4) << 2, cl = lane & 15;
#pragma unroll
    for (int m = 0; m < 4; ++m)
#pragma unroll
        for (int n = 0; n < 4; ++n) {
#pragma unroll
            for (int r = 0; r < 4; ++r) {
                int nrow = nrow0 + wr + m * 16 + r4 + r;
                int mcol = mcol0 + wc + n * 16 + cl;
                S[((size_t)(b * NN + nrow)) * NN + mcol] = acc[m][n][r];
            }
        }
}

// ---------- softmax rows of S (+mask), write P bf16 in-place ----------
__global__ __launch_bounds__(256) void k_softmax(float* __restrict__ S,
                                                 const float* __restrict__ mask) {
    int row = blockIdx.x;          // b*NN + n
    int b = row >> 11;
    float* srow = S + (size_t)row * NN;
    const float4* S4 = (const float4*)srow;
    const float4* M4 = (const float4*)(mask + (size_t)b * NN);
    int t = threadIdx.x;
    float4 a0 = S4[t], a1 = S4[t + 256];
    float4 m0 = M4[t], m1 = M4[t + 256];
    float v[8];
    v[0] = a0.x + m0.x; v[1] = a0.y + m0.y; v[2] = a0.z + m0.z; v[3] = a0.w + m0.w;
    v[4] = a1.x + m1.x; v[5] = a1.y + m1.y; v[6] = a1.z + m1.z; v[7] = a1.w + m1.w;
    float mx = v[0];
#pragma unroll
    for (int i = 1; i < 8; ++i) mx = fmaxf(mx, v[i]);
#pragma unroll
    for (int off = 32; off; off >>= 1) mx = fmaxf(mx, __shfl_xor(mx, off));
    __shared__ float redm[4], reds[4];
    int lane = t & 63, wave = t >> 6;
    if (lane == 0) redm[wave] = mx;
    __syncthreads();
    mx = fmaxf(fmaxf(redm[0], redm[1]), fmaxf(redm[2], redm[3]));
    float s = 0.f;
#pragma unroll
    for (int i = 0; i < 8; ++i) { v[i] = __expf(v[i] - mx); s += v[i]; }
#pragma unroll
    for (int off = 32; off; off >>= 1) s += __shfl_xor(s, off);
    if (lane == 0) reds[wave] = s;
    __syncthreads();
    s = reds[0] + reds[1] + reds[2] + reds[3];
    float inv = 1.0f / s;
    ushort4 w0, w1;
    w0.x = f2bf(v[0] * inv); w0.y = f2bf(v[1] * inv);
    w0.z = f2bf(v[2] * inv); w0.w = f2bf(v[3] * inv);
    w1.x = f2bf(v[4] * inv); w1.y = f2bf(v[5] * inv);
    w1.z = f2bf(v[6] * inv); w1.w = f2bf(v[7] * inv);
    ushort4* prow4 = (ushort4*)srow;   // all reads done before first __syncthreads
    prow4[t] = w0;
    prow4[t + 256] = w1;
}

// ---------- PV: out[b][n][d] = sum_m P[n][m] * X[b][m][d] ----------
// 8 waves (2M x 4N, 64x64 each), BM=128 BN=256 BK=64, 3-buffer depth-2
// prefetch, 4 phases per K-tile, one barrier + one vmcnt(6) per K-tile.
// LDS layout in dyn[]: A buffers at i*8192, B buffers at 24576 + i*16384.
__global__ __launch_bounds__(512, 2) void k_pv(const float* __restrict__ Sbuf,
                                               const unsigned short* __restrict__ XT,
                                               float* __restrict__ Out) {
    extern __shared__ unsigned short dyn[];
    int t = threadIdx.x, lane = t & 63, wave = t >> 6;
    int wm = wave >> 2, wn = wave & 3;
    // XCD-aware swizzle of the 256-block grid (nwg % 8 == 0)
    int bid = blockIdx.x + 16 * (blockIdx.y + 4 * blockIdx.z);
    int sbid = (bid & 7) * 32 + (bid >> 3);
    int bx = sbid & 15;
    int by = (sbid >> 4) & 3;
    int b = sbid >> 6;
    int nrow0 = bx * 128, d0 = by * 256;
    const unsigned short* Pb = (const unsigned short*)Sbuf + (size_t)(b * NN + nrow0) * (NN * 2);
    const unsigned short* XTb = XT + (size_t)b * DD * NN + (size_t)d0 * NN;
    f32x4 acc[4][4] = {};
    // prologue: tiles 0 and 1
    stage_part<128, 64, 512, 0, 2>(Pb, NN * 2, dyn, t);
    stage_part<256, 64, 512, 0, 4>(XTb, NN, dyn + 24576, t);
    stage_part<128, 64, 512, 0, 2>(Pb + 64, NN * 2, dyn + 8192, t);
    stage_part<256, 64, 512, 0, 4>(XTb + 64, NN, dyn + 24576 + 16384, t);
    constexpr int NT = NN / 64;   // 32
    int cur = 0;
    for (int kt = 0; kt < NT; ++kt) {
        int st = (cur >= 1) ? cur - 1 : 2;          // (cur+2)%3
        const unsigned short* An = Pb + (kt + 2) * 64;
        const unsigned short* Bn = XTb + (kt + 2) * 64;
        bool pf = (kt + 2 < NT);
        CFENCE();
        BARRIER();                 // all waves done reading buf[(kt-1)%3]
        if (kt == NT - 1) { VMCNT(0); } else { VMCNT(6); }   // tile kt landed
        CFENCE();
        const unsigned short* A = dyn + cur * 8192;
        const unsigned short* Bt = dyn + 24576 + cur * 16384;
        unsigned short* Ast = dyn + st * 8192;
        unsigned short* Bst = dyn + 24576 + st * 16384;
#pragma unroll
        for (int p = 0; p < 4; ++p) {
            int mq = p >> 1, nq = p & 1;
            if (pf) {
                if (p == 0)      stage_part<128, 64, 512, 0, 2>(An, NN * 2, Ast, t);
                else if (p == 1) stage_part<256, 64, 512, 0, 2>(Bn, NN, Bst, t);
                else if (p == 2) stage_part<256, 64, 512, 2, 4>(Bn, NN, Bst, t);
            }
            bf16x8 pa[2][2], vb[2][2];
#pragma unroll
            for (int m = 0; m < 2; ++m)
#pragma unroll
                for (int ks = 0; ks < 2; ++ks)
                    pa[m][ks] = ldsfrag<64>(A, wm * 64 + mq * 32 + m * 16, ks, lane);
#pragma unroll
            for (int n = 0; n < 2; ++n)
#pragma unroll
                for (int ks = 0; ks < 2; ++ks)
                    vb[n][ks] = ldsfrag<64>(Bt, wn * 64 + nq * 32 + n * 16, ks, lane);
            __builtin_amdgcn_s_setprio(1);
#pragma unroll
            for (int ks = 0; ks < 2; ++ks)
#pragma unroll
                for (int m = 0; m < 2; ++m)
#pragma unroll
                    for (int n = 0; n < 2; ++n)
                        acc[mq * 2 + m][nq * 2 + n] =
                            MFMA(pa[m][ks], vb[n][ks], acc[mq * 2 + m][nq * 2 + n]);
            __builtin_amdgcn_s_setprio(0);
        }
        cur = (cur == 2) ? 0 : cur + 1;
    }
    int r4 = (lane >> 4) << 2, cl = lane & 15;
#pragma unroll
    for (int mi = 0; mi < 4; ++mi)
#pragma unroll
        for (int ni = 0; ni < 4; ++ni) {
#pragma unroll
            for (int r = 0; r < 4; ++r) {
                int row = b * NN + nrow0 + wm * 64 + mi * 16 + r4 + r;
                int dc = d0 + wn * 64 + ni * 16 + cl;
                Out[(size_t)row * DD + dc] = acc[mi][ni][r];
            }
        }
}

extern "C" void kernel_launch(void* const* d_in, const int* in_sizes, int n_in,
                              void* d_out, int out_size, void* d_ws, size_t ws_size,
                              hipStream_t stream) {
    const float* X    = (const float*)d_in[0];
    const float* mask = (const float*)d_in[1];
    const float* Wq   = (const float*)d_in[2];
    const float* bq   = (const float*)d_in[3];
    const float* Wk   = (const float*)d_in[4];
    const float* bk   = (const float*)d_in[5];
    float* Out = (float*)d_out;

    unsigned short* Xh   = (unsigned short*)d_ws;
    unsigned short* Xl   = Xh + (size_t)BB * NN * DD;
    unsigned short* XT   = Xl + (size_t)BB * NN * DD;
    unsigned short* WqTh = XT + (size_t)BB * NN * DD;
    unsigned short* WqTl = WqTh + (size_t)AA * DD;
    unsigned short* WkTh = WqTl + (size_t)AA * DD;
    unsigned short* WkTl = WkTh + (size_t)AA * DD;
    unsigned short* Qh   = WkTl + (size_t)AA * DD;
    unsigned short* Ql   = Qh + (size_t)BB * NN * AA;
    unsigned short* Kh   = Ql + (size_t)BB * NN * AA;
    unsigned short* Kl   = Kh + (size_t)BB * NN * AA;
    float* S = (float*)(Kl + (size_t)BB * NN * AA);

    hipFuncSetAttribute((const void*)k_pv,
                        hipFuncAttributeMaxDynamicSharedMemorySize, 147456);

    k_prep<<<dim3(NN / 64, DD / 64, BB), 256, 0, stream>>>(X, Xh, Xl, XT);
    k_wsplit<<<dim3((AA * DD) / 256), 256, 0, stream>>>(Wq, WqTh, WqTl);
    k_wsplit<<<dim3((AA * DD) / 256), 256, 0, stream>>>(Wk, WkTh, WkTl);

    k_proj<<<dim3((BB * NN) / 64, 4), 256, 0, stream>>>(Xh, Xl, WqTh, WqTl, WkTh, WkTl,
                                                        bq, bk, Qh, Ql, Kh, Kl);

    k_scores<<<dim3(NN / 128, NN / 128, BB), 256, 0, stream>>>(Qh, Ql, Kh, Kl, S);
    k_softmax<<<dim3(BB * NN), 256, 0, stream>>>(S, mask);
    k_pv<<<dim3(16, 4, BB), 512, 147456, stream>>>(S, XT, Out);
}